// Round 2
// baseline (1506.676 us; speedup 1.0000x reference)
//
#include <hip/hip_runtime.h>
#include <stdint.h>

#define B_ROWS 16384
#define E_DIM 1024
#define H_N 16

typedef unsigned short u16;
typedef __attribute__((ext_vector_type(4))) float f32x4;
typedef __attribute__((ext_vector_type(4))) unsigned short u16x4;
typedef __attribute__((ext_vector_type(8))) short bf16x8;

static __device__ __forceinline__ u16 f2bf(float f) {
  union { float f; unsigned u; } x; x.f = f;
  unsigned r = (x.u + 0x7FFFu + ((x.u >> 16) & 1u)) >> 16;
  return (u16)r;
}
static __device__ __forceinline__ float bf2f(u16 h) {
  union { unsigned u; float f; } x; x.u = ((unsigned)h) << 16;
  return x.f;
}

typedef const __attribute__((address_space(1))) void gvoid;
typedef __attribute__((address_space(3))) void lvoid;
static __device__ __forceinline__ void gload16(const void* g, void* l) {
  __builtin_amdgcn_global_load_lds((gvoid*)g, (lvoid*)l, 16, 0, 0);
}

// ---------------- f32 -> bf16 convert ----------------
__global__ __launch_bounds__(256) void cvt_f32_bf16(const float* __restrict__ in,
                                                    u16* __restrict__ out, int n4) {
  int stride = gridDim.x * blockDim.x;
  for (int i = blockIdx.x * blockDim.x + threadIdx.x; i < n4; i += stride) {
    f32x4 v = ((const f32x4*)in)[i];
    u16x4 o;
    o.x = f2bf(v.x); o.y = f2bf(v.y); o.z = f2bf(v.z); o.w = f2bf(v.w);
    ((u16x4*)out)[i] = o;
  }
}

// ---------------- transpose f32 [n x n] -> bf16 [n x n]^T ----------------
__global__ __launch_bounds__(256) void transpose_to_bf16(const float* __restrict__ in,
                                                         u16* __restrict__ out, int n) {
  __shared__ float t[32][33];
  int bx = blockIdx.x * 32;  // input col base
  int by = blockIdx.y * 32;  // input row base
  int tx = threadIdx.x, ty = threadIdx.y;  // 32 x 8
  for (int r = ty; r < 32; r += 8)
    t[r][tx] = in[(size_t)(by + r) * n + bx + tx];
  __syncthreads();
  for (int r = ty; r < 32; r += 8)
    out[(size_t)(bx + r) * n + by + tx] = f2bf(t[tx][r]);
}

// ---------------- folded bias: cb[j] = b_fuse[j] + sum_f sum_i b_out_f[i]*w_fuse[j, f*E+i]
__global__ __launch_bounds__(256) void fold_bias(const float* __restrict__ b0,
                                                 const float* __restrict__ b1,
                                                 const float* __restrict__ b2,
                                                 const float* __restrict__ wfuse,
                                                 const float* __restrict__ bfuse,
                                                 float* __restrict__ cb) {
  int wave = threadIdx.x >> 6, lane = threadIdx.x & 63;
  int j = blockIdx.x * 4 + wave;
  const float* wrow = wfuse + (size_t)j * (3 * E_DIM);
  float s = 0.f;
  for (int i = lane; i < E_DIM; i += 64) s += b0[i] * wrow[i];
  for (int i = lane; i < E_DIM; i += 64) s += b1[i] * wrow[E_DIM + i];
  for (int i = lane; i < E_DIM; i += 64) s += b2[i] * wrow[2 * E_DIM + i];
  for (int off = 32; off; off >>= 1) s += __shfl_xor(s, off);
  if (lane == 0) cb[j] = bfuse[j] + s;
}

// ---------------- GEMM: C[m,n] = sum_k A[m,k]*W[n,k] (+bias[n]) ----------------
// A bf16 [M,K] lda; W bf16 [N,K] ldw; tiles 128x128x64, 4 waves, 16x16x32 MFMA.
// MODE 0: C bf16 = acc + bias(optional)
// MODE 1: C f32  = acc + bias
// MODE 2: C f32 += acc
#define BM 128
#define BN 128
#define BK 64

template <int MODE>
__global__ __launch_bounds__(256) void gemm_nt(const u16* __restrict__ A,
                                               const u16* __restrict__ W,
                                               void* __restrict__ Cp,
                                               const float* __restrict__ bias,
                                               int lda, int ldw, int ldc, int K) {
  __shared__ __align__(16) u16 As[BM * BK];
  __shared__ __align__(16) u16 Bs[BN * BK];

  const int tid = threadIdx.x;
  const int wave = tid >> 6;
  const int lane = tid & 63;
  const int wm = wave >> 1;       // 2x2 wave grid, each wave owns 64x64
  const int wn = wave & 1;
  const int l16 = lane & 15;
  const int kq = lane >> 4;       // 0..3
  const int bm = blockIdx.y;
  const int bn = blockIdx.x;

  const int srow = lane >> 3;          // 0..7 row within 8-row chunk
  const int scol = (lane & 7) * 8;     // col start (8 bf16 = 16B)

  const u16* Abase = A + (size_t)bm * BM * lda + scol;
  const u16* Wbase = W + (size_t)bn * BN * ldw + scol;

  f32x4 acc[4][4];
#pragma unroll
  for (int i = 0; i < 4; i++)
#pragma unroll
    for (int j = 0; j < 4; j++) acc[i][j] = (f32x4){0.f, 0.f, 0.f, 0.f};

  for (int k0 = 0; k0 < K; k0 += BK) {
#pragma unroll
    for (int i = 0; i < 4; i++) {
      int c = wave * 4 + i;                 // chunk 0..15, 8 rows each
      int row = c * 8 + srow;
      gload16(Abase + (size_t)row * lda + k0, &As[c * 512]);
    }
#pragma unroll
    for (int i = 0; i < 4; i++) {
      int c = wave * 4 + i;
      int row = c * 8 + srow;
      gload16(Wbase + (size_t)row * ldw + k0, &Bs[c * 512]);
    }
    __syncthreads();  // drains vmcnt (compiler emits full waitcnt before barrier)
#pragma unroll
    for (int kk = 0; kk < 2; kk++) {
      bf16x8 af[4], bf[4];
#pragma unroll
      for (int mi = 0; mi < 4; mi++)
        af[mi] = *(const bf16x8*)&As[(wm * 64 + mi * 16 + l16) * BK + kk * 32 + kq * 8];
#pragma unroll
      for (int ni = 0; ni < 4; ni++)
        bf[ni] = *(const bf16x8*)&Bs[(wn * 64 + ni * 16 + l16) * BK + kk * 32 + kq * 8];
#pragma unroll
      for (int mi = 0; mi < 4; mi++)
#pragma unroll
        for (int ni = 0; ni < 4; ni++)
          acc[mi][ni] = __builtin_amdgcn_mfma_f32_16x16x32_bf16(af[mi], bf[ni], acc[mi][ni], 0, 0, 0);
    }
    __syncthreads();
  }

  const int r0 = kq * 4;  // C/D layout: col = lane&15, row = (lane>>4)*4 + r
#pragma unroll
  for (int mi = 0; mi < 4; mi++) {
#pragma unroll
    for (int ni = 0; ni < 4; ni++) {
      int row = bm * BM + wm * 64 + mi * 16 + r0;
      int col = bn * BN + wn * 64 + ni * 16 + l16;
      if (MODE == 0) {
        u16* C = (u16*)Cp;
        float bv = bias ? bias[col] : 0.f;
#pragma unroll
        for (int r = 0; r < 4; r++)
          C[(size_t)(row + r) * ldc + col] = f2bf(acc[mi][ni][r] + bv);
      } else if (MODE == 1) {
        float* C = (float*)Cp;
        float bv = bias[col];
#pragma unroll
        for (int r = 0; r < 4; r++)
          C[(size_t)(row + r) * ldc + col] = acc[mi][ni][r] + bv;
      } else {
        float* C = (float*)Cp;
#pragma unroll
        for (int r = 0; r < 4; r++)
          C[(size_t)(row + r) * ldc + col] += acc[mi][ni][r];
      }
    }
  }
}

// ---------------- attention combine: softmax over 2 kv slots, per (b,h) wave ----
// O[b, h*64+d] = w1*V1 + w2*V2 ; O may alias Q (read-before-write per thread).
__global__ __launch_bounds__(256) void attn_combine(const u16* __restrict__ Q,
                                                    const u16* __restrict__ KV1,
                                                    const u16* __restrict__ KV2,
                                                    u16* __restrict__ O) {
  int gw = blockIdx.x * 4 + (threadIdx.x >> 6);
  int lane = threadIdx.x & 63;
  int b = gw >> 4, h = gw & 15;
  size_t qo = (size_t)b * E_DIM + h * 64 + lane;
  size_t ko = (size_t)b * (2 * E_DIM) + h * 64 + lane;
  float q = bf2f(Q[qo]);
  float k1 = bf2f(KV1[ko]), k2 = bf2f(KV2[ko]);
  float v1 = bf2f(KV1[ko + E_DIM]), v2 = bf2f(KV2[ko + E_DIM]);
  float s1 = q * k1, s2 = q * k2;
  for (int off = 32; off; off >>= 1) {
    s1 += __shfl_xor(s1, off);
    s2 += __shfl_xor(s2, off);
  }
  s1 *= 0.125f; s2 *= 0.125f;  // 1/sqrt(64)
  float m = fmaxf(s1, s2);
  float e1 = __expf(s1 - m), e2 = __expf(s2 - m);
  float rn = 1.f / (e1 + e2);
  O[qo] = f2bf((e1 * rn) * v1 + (e2 * rn) * v2);
}

// ---------------- layernorm in place on f32 [B,1024] ----------------
__global__ __launch_bounds__(256) void layernorm_inplace(float* __restrict__ y,
                                                         const float* __restrict__ g,
                                                         const float* __restrict__ b) {
  int row = blockIdx.x, tid = threadIdx.x;
  float* yr = y + (size_t)row * E_DIM;
  f32x4 v = ((const f32x4*)yr)[tid];
  float s = v.x + v.y + v.z + v.w;
  float sq = v.x * v.x + v.y * v.y + v.z * v.z + v.w * v.w;
  for (int off = 32; off; off >>= 1) {
    s += __shfl_xor(s, off);
    sq += __shfl_xor(sq, off);
  }
  __shared__ float rs[4], rq[4];
  int wave = tid >> 6, lane = tid & 63;
  if (lane == 0) { rs[wave] = s; rq[wave] = sq; }
  __syncthreads();
  s = rs[0] + rs[1] + rs[2] + rs[3];
  sq = rq[0] + rq[1] + rq[2] + rq[3];
  float mu = s * (1.f / E_DIM);
  float var = sq * (1.f / E_DIM) - mu * mu;
  float rstd = rsqrtf(var + 1e-5f);
  f32x4 gg = ((const f32x4*)g)[tid];
  f32x4 bb = ((const f32x4*)b)[tid];
  f32x4 o;
  o.x = (v.x - mu) * rstd * gg.x + bb.x;
  o.y = (v.y - mu) * rstd * gg.y + bb.y;
  o.z = (v.z - mu) * rstd * gg.z + bb.z;
  o.w = (v.w - mu) * rstd * gg.w + bb.w;
  ((f32x4*)yr)[tid] = o;
}

extern "C" void kernel_launch(void* const* d_in, const int* in_sizes, int n_in,
                              void* d_out, int out_size, void* d_ws, size_t ws_size,
                              hipStream_t stream) {
  const float* feat[3] = {(const float*)d_in[0], (const float*)d_in[1], (const float*)d_in[2]};
  const float* w_in[3] = {(const float*)d_in[3], (const float*)d_in[7], (const float*)d_in[11]};
  const float* b_in[3] = {(const float*)d_in[4], (const float*)d_in[8], (const float*)d_in[12]};
  const float* w_out[3] = {(const float*)d_in[5], (const float*)d_in[9], (const float*)d_in[13]};
  const float* b_out[3] = {(const float*)d_in[6], (const float*)d_in[10], (const float*)d_in[14]};
  const float* w_fuse = (const float*)d_in[15];
  const float* b_fuse = (const float*)d_in[16];
  const float* ln_g = (const float*)d_in[17];
  const float* ln_b = (const float*)d_in[18];

  auto A256 = [](size_t b) { return (b + 255) & ~(size_t)255; };
  const size_t EE2 = (size_t)E_DIM * E_DIM * 2;     // 2 MB (bf16 E x E)
  const size_t E3E2 = 3 * EE2;                      // 6 MB (bf16 3E x E)

  // Persistent region: winbf[3] + Mf[3] + cb
  const size_t persist = 3 * A256(E3E2) + 3 * A256(EE2) + A256(E_DIM * 4);

  // Pick largest chunk CH (rows) such that persist + pool(CH) <= ws_size.
  // pool(CH) = fb[3] + Qb + KV1 + KV2 = CH*2048*4 + CH*4096*2 = CH*16384 bytes.
  int CH = B_ROWS;
  while (CH > 512) {
    size_t pool = 4 * A256((size_t)CH * E_DIM * 2) + 2 * A256((size_t)CH * 2 * E_DIM * 2);
    if (persist + pool <= ws_size) break;
    CH >>= 1;
  }

  char* p = (char*)d_ws;
  auto alloc = [&](size_t bytes) {
    void* r = (void*)p;
    p += A256(bytes);
    return r;
  };

  u16* winbf[3];
  for (int i = 0; i < 3; i++) winbf[i] = (u16*)alloc(E3E2);
  u16* Mf[3];
  for (int i = 0; i < 3; i++) Mf[i] = (u16*)alloc(EE2);
  float* cb = (float*)alloc(E_DIM * 4);

  char* pool = p;  // transient region, reused between stage 1 and stage 2

  // ---- stage 0/1: weight conversions + folded fuse weights ----
  {
    u16* wfusebf = (u16*)pool;
    u16* woutT = (u16*)(pool + A256(E3E2));
    for (int i = 0; i < 3; i++)
      cvt_f32_bf16<<<256, 256, 0, stream>>>(w_in[i], winbf[i], 3 * E_DIM * E_DIM / 4);
    cvt_f32_bf16<<<256, 256, 0, stream>>>(w_fuse, wfusebf, 3 * E_DIM * E_DIM / 4);
    dim3 tb(32, 8);
    for (int f = 0; f < 3; f++) {
      transpose_to_bf16<<<dim3(E_DIM / 32, E_DIM / 32), tb, 0, stream>>>(w_out[f], woutT, E_DIM);
      // M_f = w_fuse[:, fE:(f+1)E] @ w_out_f   (both operands K-contiguous)
      gemm_nt<0><<<dim3(E_DIM / BN, E_DIM / BM), 256, 0, stream>>>(
          wfusebf + f * E_DIM, woutT, (void*)Mf[f], nullptr, 3 * E_DIM, E_DIM, E_DIM, E_DIM);
    }
    fold_bias<<<E_DIM / 4, 256, 0, stream>>>(b_out[0], b_out[1], b_out[2], w_fuse, b_fuse, cb);
  }

  // ---- stage 2: chunk-outer, MHA-inner ----
  {
    char* q = pool;
    auto palloc = [&](size_t bytes) {
      void* r = (void*)q;
      q += A256(bytes);
      return r;
    };
    u16* fb[3];
    for (int i = 0; i < 3; i++) fb[i] = (u16*)palloc((size_t)CH * E_DIM * 2);
    u16* Qb = (u16*)palloc((size_t)CH * E_DIM * 2);
    u16* KV1 = (u16*)palloc((size_t)CH * 2 * E_DIM * 2);
    u16* KV2 = (u16*)palloc((size_t)CH * 2 * E_DIM * 2);

    const int kvidx[3][2] = {{1, 2}, {0, 2}, {0, 1}};
    for (int row0 = 0; row0 < B_ROWS; row0 += CH) {
      const int n4 = CH * E_DIM / 4;
      for (int i = 0; i < 3; i++)
        cvt_f32_bf16<<<1024, 256, 0, stream>>>(feat[i] + (size_t)row0 * E_DIM, fb[i], n4);
      for (int m = 0; m < 3; m++) {
        // Q = feat_m @ wq^T + bq   [CH, E]
        gemm_nt<0><<<dim3(E_DIM / BN, CH / BM), 256, 0, stream>>>(
            fb[m], winbf[m], (void*)Qb, b_in[m], E_DIM, E_DIM, E_DIM, E_DIM);
        // KV_j = feat_kvj @ [wk;wv]^T + [bk;bv]   [CH, 2E]
        gemm_nt<0><<<dim3(2 * E_DIM / BN, CH / BM), 256, 0, stream>>>(
            fb[kvidx[m][0]], winbf[m] + (size_t)E_DIM * E_DIM, (void*)KV1, b_in[m] + E_DIM,
            E_DIM, E_DIM, 2 * E_DIM, E_DIM);
        gemm_nt<0><<<dim3(2 * E_DIM / BN, CH / BM), 256, 0, stream>>>(
            fb[kvidx[m][1]], winbf[m] + (size_t)E_DIM * E_DIM, (void*)KV2, b_in[m] + E_DIM,
            E_DIM, E_DIM, 2 * E_DIM, E_DIM);
        // softmax over 2 kv slots; write O over Q (safe aliasing, per-thread RMW)
        attn_combine<<<CH * H_N / 4, 256, 0, stream>>>(Qb, KV1, KV2, Qb);
        // y (+)= O @ M_f^T (+ cb on first MHA)
        float* yout = (float*)d_out + (size_t)row0 * E_DIM;
        if (m == 0)
          gemm_nt<1><<<dim3(E_DIM / BN, CH / BM), 256, 0, stream>>>(
              Qb, Mf[0], (void*)yout, cb, E_DIM, E_DIM, E_DIM, E_DIM);
        else
          gemm_nt<2><<<dim3(E_DIM / BN, CH / BM), 256, 0, stream>>>(
              Qb, Mf[m], (void*)yout, nullptr, E_DIM, E_DIM, E_DIM, E_DIM);
      }
    }
  }

  // ---- stage 3: layernorm in place on d_out ----
  layernorm_inplace<<<B_ROWS, 256, 0, stream>>>((float*)d_out, ln_g, ln_b);
}